// Round 4
// baseline (322.745 us; speedup 1.0000x reference)
//
#include <hip/hip_runtime.h>

typedef unsigned short u16;
typedef unsigned int u32;
typedef __attribute__((ext_vector_type(8))) short bf16x8;
typedef __attribute__((ext_vector_type(4))) float f32x4;
typedef __attribute__((ext_vector_type(2))) float f32x2;
typedef __attribute__((ext_vector_type(8))) u16 u16x8;
typedef __attribute__((ext_vector_type(4))) u16 u16x4;
typedef __attribute__((ext_vector_type(2))) u16 u16x2;
typedef __attribute__((ext_vector_type(2))) u32 u32x2;

#define DIM 128
#define MT 64    // m-tile (nodes) per gemm block
#define AS1C(p) ((const __attribute__((address_space(1))) void*)(p))
#define AS3P(p) ((__attribute__((address_space(3))) void*)(p))

__device__ __forceinline__ u32 f2bf(float f){
  u32 x = __float_as_uint(f);
  return (x + 0x7fffu + ((x >> 16) & 1u)) >> 16;
}
__device__ __forceinline__ float bf2f(u16 u){
  return __uint_as_float(((u32)u) << 16);
}

// ---------------- prep: build W (bf16, transposed, concat) + zero cnt --------
// Column layout (global col c, ncol = (3T+1)*128):
//   c in [0, 2T*128): per type t (256 cols each): even -> Wq[t][:,j], odd -> Wv[t][:,j]
//   c in [2T*128, 3T*128): k blocks: Wk[t][:,j]
//   c in [3T*128, ...): mean_t Ws[t][:,j]
__global__ __launch_bounds__(256) void prep_kernel(
    const float* __restrict__ Wk, const float* __restrict__ bk,
    const float* __restrict__ Wq, const float* __restrict__ bq,
    const float* __restrict__ Wv, const float* __restrict__ bv,
    const float* __restrict__ Ws, const float* __restrict__ bb,
    u16* __restrict__ WcatT, float* __restrict__ biascat,
    int* __restrict__ cnt, int T, int N){
  int id = blockIdx.x * 256 + threadIdx.x;
  int total_w = (3 * T + 1) * DIM * DIM;
  if (id >= total_w){
    int z = id - total_w;
    if (z < N) cnt[z] = 0;
    return;
  }
  int kk = id & (DIM - 1);
  int c  = id >> 7;
  int qvspan = 2 * T * DIM;
  float wv, bvv;
  if (c < qvspan){
    int t = c >> 8;
    int w = c & 255;
    int j = w >> 1;
    if ((w & 1) == 0){ wv = Wq[(t*DIM + kk)*DIM + j]; bvv = bq[t*DIM + j]; }
    else             { wv = Wv[(t*DIM + kk)*DIM + j]; bvv = bv[t*DIM + j]; }
  } else if (c < qvspan + T * DIM){
    int t = (c - qvspan) >> 7;
    int j = (c - qvspan) & (DIM - 1);
    wv = Wk[(t*DIM + kk)*DIM + j]; bvv = bk[t*DIM + j];
  } else {
    int j = c - 3 * T * DIM;
    float s = 0.f, sb = 0.f;
    for (int t = 0; t < T; ++t){ s += Ws[(t*DIM + kk)*DIM + j]; sb += bb[t*DIM + j]; }
    wv = s / (float)T; bvv = sb / (float)T;
  }
  WcatT[(size_t)c * DIM + kk] = (u16)f2bf(wv);
  if (kk == 0) biascat[c] = bvv;
}

// ---------------- CSR build --------------------------------------------------
__global__ __launch_bounds__(256) void hist_kernel(const int* __restrict__ dst,
                                                   int* __restrict__ cnt,
                                                   int* __restrict__ rank, int E){
  int e = blockIdx.x * 256 + threadIdx.x;
  if (e < E) rank[e] = atomicAdd(&cnt[dst[e]], 1);
}

__global__ __launch_bounds__(256) void scan1_kernel(const int* __restrict__ cnt,
                                                    int* __restrict__ offs,
                                                    int* __restrict__ bsum, int n){
  __shared__ int wsum[4];
  const int tid = threadIdx.x;
  const int lane = tid & 63, wave = tid >> 6;
  const int base = blockIdx.x * 2048 + tid * 8;
  int v[8]; int tot = 0;
#pragma unroll
  for (int j = 0; j < 8; ++j){
    int idx = base + j;
    int val = (idx < n) ? cnt[idx] : 0;
    v[j] = val; tot += val;
  }
  int incl = tot;
#pragma unroll
  for (int d = 1; d < 64; d <<= 1){
    int u = __shfl_up(incl, d, 64);
    if (lane >= d) incl += u;
  }
  if (lane == 63) wsum[wave] = incl;
  __syncthreads();
  int wbase = 0;
#pragma unroll
  for (int w = 0; w < 4; ++w) if (w < wave) wbase += wsum[w];
  int excl = wbase + incl - tot;
  if (tid == 255) bsum[blockIdx.x] = wbase + incl;
#pragma unroll
  for (int j = 0; j < 8; ++j){
    int idx = base + j;
    if (idx < n) offs[idx] = excl;
    excl += v[j];
  }
}

__global__ __launch_bounds__(64) void scan2_kernel(const int* __restrict__ bsum,
                                                   int* __restrict__ boffs,
                                                   int nb, int* __restrict__ offs, int n){
  int lane = threadIdx.x;
  int v = (lane < nb) ? bsum[lane] : 0;
  int incl = v;
#pragma unroll
  for (int d = 1; d < 64; d <<= 1){
    int u = __shfl_up(incl, d, 64);
    if (lane >= d) incl += u;
  }
  if (lane < nb) boffs[lane] = incl - v;
  if (lane == 63) offs[n] = incl;
}

__global__ __launch_bounds__(256) void scan3_kernel(int* __restrict__ offs,
                                                    const int* __restrict__ boffs, int n){
  int base = blockIdx.x * 2048 + threadIdx.x * 8;
  int add = boffs[blockIdx.x];
#pragma unroll
  for (int j = 0; j < 8; ++j){
    int idx = base + j;
    if (idx < n) offs[idx] += add;
  }
}

__global__ __launch_bounds__(256) void scatter_kernel(const int* __restrict__ src,
                                                      const int* __restrict__ dst,
                                                      const int* __restrict__ et,
                                                      const int* __restrict__ offs,
                                                      const int* __restrict__ rank,
                                                      int* __restrict__ packed, int E){
  int e = blockIdx.x * 256 + threadIdx.x;
  if (e >= E) return;
  int pos = offs[dst[e]] + rank[e];
  packed[pos] = (src[e] << 2) | (et[e] & 3);
}

// ---------------- GEMM: Y = x @ Wcat + bias (bf16 out) -----------------------
// One block per 64-node m-tile. x staged ONCE (fp32->bf16 in-kernel, swizzled),
// x-fragments held in registers, then loop over 13 n-tiles staging only the
// 32 KB W-tile via swizzled global_load_lds (L2-resident).
// XOR swizzle: physical 8-elem block p of row r holds logical block p^(r&7).
// D mapping (mfma_16x16x32_bf16, A=W^T frag, B=x frag):
//   col(=node) = lane&15, row(=feat) = quad*4 + reg
__global__ __launch_bounds__(256, 3) void gemm_kernel(const float* __restrict__ x,
                                                      const u16* __restrict__ WcatT,
                                                      const float* __restrict__ biascat,
                                                      u16* __restrict__ Y,
                                                      int N, int ncol, int ntiles){
  __shared__ u16 xt[MT * DIM];     // 16 KB
  __shared__ u16 wt[DIM * DIM];    // 32 KB
  const int m0 = blockIdx.x * MT;
  const int tid  = threadIdx.x;
  const int wave = tid >> 6;
  const int lane = tid & 63;
  const int l15  = lane & 15;
  const int quad = lane >> 4;

  // ---- stage x: thread t -> row r = t>>2, quarter q = t&3 (k = q*32..q*32+31)
  {
    int r = tid >> 2;
    int q = tid & 3;
    int node = m0 + r;
    u16 tmp[32];
    if (node < N){
      const float* xp = x + (size_t)node * DIM + q * 32;
#pragma unroll
      for (int j = 0; j < 8; ++j){
        f32x4 v = *(const f32x4*)(xp + j * 4);
        tmp[j*4+0] = (u16)f2bf(v.x); tmp[j*4+1] = (u16)f2bf(v.y);
        tmp[j*4+2] = (u16)f2bf(v.z); tmp[j*4+3] = (u16)f2bf(v.w);
      }
    } else {
#pragma unroll
      for (int j = 0; j < 32; ++j) tmp[j] = 0;
    }
#pragma unroll
    for (int i = 0; i < 4; ++i){
      int lb = 4 * q + i;
      int pb = lb ^ (r & 7);
      *(u16x8*)&xt[r * DIM + pb * 8] = *(const u16x8*)&tmp[i * 8];
    }
  }
  __syncthreads();

  // ---- preload x fragments (K=128 -> 4 k-steps of 32)
  bf16x8 bfr[4];
  {
    int row = wave * 16 + l15;
#pragma unroll
    for (int ks = 0; ks < 4; ++ks){
      int pb = (ks * 4 + quad) ^ (l15 & 7);
      bfr[ks] = *(const bf16x8*)&xt[row * DIM + pb * 8];
    }
  }

  const int node = m0 + wave * 16 + l15;
  const size_t rowbase = (size_t)node * ncol;

  for (int nt = 0; nt < ntiles; ++nt){
    const int n0 = nt * DIM;
    __syncthreads();            // all reads of wt from prev iter done
    // stage W tile: 2048 slots of 16B, lane-consecutive LDS dests
#pragma unroll
    for (int it = 0; it < 8; ++it){
      int s  = it * 256 + tid;
      int r  = s >> 4;
      int p  = s & 15;
      int lb = p ^ (r & 7);
      int lbase = (it * 256 + wave * 64) * 8;   // wave-uniform base, +lane*16B
      __builtin_amdgcn_global_load_lds(AS1C(WcatT + (size_t)(n0 + r) * DIM + lb * 8),
                                       AS3P(wt + lbase), 16, 0, 0);
    }
    __syncthreads();

    f32x4 acc[8];
#pragma unroll
    for (int f = 0; f < 8; ++f) acc[f] = (f32x4){0.f, 0.f, 0.f, 0.f};
#pragma unroll
    for (int ks = 0; ks < 4; ++ks){
      bf16x8 afr[8];
#pragma unroll
      for (int f = 0; f < 8; ++f)
        afr[f] = *(const bf16x8*)&wt[(f * 16 + l15) * DIM + (((ks * 4 + quad) ^ (l15 & 7)) * 8)];
#pragma unroll
      for (int f = 0; f < 8; ++f)
        acc[f] = __builtin_amdgcn_mfma_f32_16x16x32_bf16(afr[f], bfr[ks], acc[f], 0, 0, 0);
    }

    if (node < N){
#pragma unroll
      for (int f = 0; f < 8; ++f){
        int feat = n0 + f * 16 + quad * 4;
        f32x4 b4 = *(const f32x4*)&biascat[feat];
        f32x4 v  = acc[f];
        u32 lo = f2bf(v.x + b4.x) | (f2bf(v.y + b4.y) << 16);
        u32 hi = f2bf(v.z + b4.z) | (f2bf(v.w + b4.w) << 16);
        u32x2 pk = {lo, hi};
        *(u32x2*)&Y[rowbase + feat] = pk;
      }
    }
  }
}

// ---------------- aggregate + epilogue: one wave per dst node ----------------
__global__ __launch_bounds__(256) void agg_kernel(const u16* __restrict__ Y,
                                                  const int* __restrict__ offs,
                                                  const int* __restrict__ packed,
                                                  float* __restrict__ out,
                                                  int N, int T, float invT, int ncol){
  const int wave = threadIdx.x >> 6;
  const int lane = threadIdx.x & 63;
  const int i = blockIdx.x * 4 + wave;
  if (i >= N) return;

  const int kqoff = 2 * T * DIM;   // 1024
  const int soff  = 3 * T * DIM;   // 1536
  const u16* yr = Y + (size_t)i * ncol;
  const int c2 = lane * 2;

  u16x2 kw0 = *(const u16x2*)(yr + kqoff + 0 * DIM + c2);
  u16x2 kw1 = *(const u16x2*)(yr + kqoff + 1 * DIM + c2);
  u16x2 kw2 = *(const u16x2*)(yr + kqoff + 2 * DIM + c2);
  u16x2 kw3 = *(const u16x2*)(yr + kqoff + 3 * DIM + c2);
  float ka[4] = { bf2f(kw0.x), bf2f(kw1.x), bf2f(kw2.x), bf2f(kw3.x) };
  float kb[4] = { bf2f(kw0.y), bf2f(kw1.y), bf2f(kw2.y), bf2f(kw3.y) };
  u16x2 sw = *(const u16x2*)(yr + soff + c2);
  float s0 = bf2f(sw.x), s1 = bf2f(sw.y);

  float acc0 = 0.f, acc1 = 0.f;
  int e = offs[i], end = offs[i + 1];
  for (; e + 8 <= end; e += 8){
    int p[8];
#pragma unroll
    for (int j = 0; j < 8; ++j)
      p[j] = __builtin_amdgcn_readfirstlane(packed[e + j]);
    u16x4 a[8];
#pragma unroll
    for (int j = 0; j < 8; ++j)
      a[j] = *(const u16x4*)(Y + (size_t)(p[j] >> 2) * ncol + (p[j] & 3) * 256 + lane * 4);
#pragma unroll
    for (int j = 0; j < 8; ++j){
      int t = p[j] & 3;
      float k0 = (t == 0) ? ka[0] : (t == 1) ? ka[1] : (t == 2) ? ka[2] : ka[3];
      float k1 = (t == 0) ? kb[0] : (t == 1) ? kb[1] : (t == 2) ? kb[2] : kb[3];
      acc0 += bf2f(a[j].y) * __builtin_amdgcn_rcpf(1.f + __expf(-(k0 + bf2f(a[j].x))));
      acc1 += bf2f(a[j].w) * __builtin_amdgcn_rcpf(1.f + __expf(-(k1 + bf2f(a[j].z))));
    }
  }
  for (; e < end; ++e){
    int p = __builtin_amdgcn_readfirstlane(packed[e]);
    int t = p & 3;
    u16x4 qv = *(const u16x4*)(Y + (size_t)(p >> 2) * ncol + t * 256 + lane * 4);
    float k0 = (t == 0) ? ka[0] : (t == 1) ? ka[1] : (t == 2) ? ka[2] : ka[3];
    float k1 = (t == 0) ? kb[0] : (t == 1) ? kb[1] : (t == 2) ? kb[2] : kb[3];
    acc0 += bf2f(qv.y) * __builtin_amdgcn_rcpf(1.f + __expf(-(k0 + bf2f(qv.x))));
    acc1 += bf2f(qv.w) * __builtin_amdgcn_rcpf(1.f + __expf(-(k1 + bf2f(qv.z))));
  }
  f32x2 o = { invT * acc0 + s0, invT * acc1 + s1 };
  *(f32x2*)&out[(size_t)i * DIM + c2] = o;
}

// ---------------- launch -----------------------------------------------------
extern "C" void kernel_launch(void* const* d_in, const int* in_sizes, int n_in,
                              void* d_out, int out_size, void* d_ws, size_t ws_size,
                              hipStream_t stream){
  const float* x  = (const float*)d_in[0];
  const int*   ei = (const int*)d_in[1];
  const int*   et = (const int*)d_in[2];
  const float* Wk = (const float*)d_in[3];
  const float* bk = (const float*)d_in[4];
  const float* Wq = (const float*)d_in[5];
  const float* bq = (const float*)d_in[6];
  const float* Wv = (const float*)d_in[7];
  const float* bv = (const float*)d_in[8];
  const float* Ws = (const float*)d_in[9];
  const float* bb = (const float*)d_in[10];
  float* out = (float*)d_out;

  const int N = in_sizes[0] / DIM;
  const int E = in_sizes[2];
  const int T = in_sizes[3] / (DIM * DIM);
  const int NB = 3 * T + 1;
  const int ncol = NB * DIM;
  const int mtiles = (N + MT - 1) / MT;
  const int nscan = (N + 2047) / 2048;

  char* ws = (char*)d_ws;
  size_t off = 0;
  auto alloc = [&](size_t bytes) -> char* {
    char* p = ws + off;
    off = (off + bytes + 255) & ~(size_t)255;
    return p;
  };
  u16*   WcatT   = (u16*)alloc((size_t)ncol * DIM * 2);
  float* biascat = (float*)alloc((size_t)ncol * 4);
  u16*   Y       = (u16*)alloc((size_t)N * ncol * 2);
  int*   cnt     = (int*)alloc((size_t)N * 4);
  int*   offs    = (int*)alloc((size_t)(N + 1) * 4);
  int*   rank    = (int*)alloc((size_t)E * 4);
  int*   packed  = (int*)alloc((size_t)E * 4);
  int*   bsum    = (int*)alloc((size_t)nscan * 4);
  int*   boffs   = (int*)alloc((size_t)nscan * 4);
  (void)ws_size; (void)n_in; (void)out_size;

  const int* srcp = ei;
  const int* dstp = ei + E;

  int prep_total = NB * DIM * DIM + N;
  prep_kernel<<<(prep_total + 255) / 256, 256, 0, stream>>>(Wk, bk, Wq, bq, Wv, bv, Ws, bb,
                                                            WcatT, biascat, cnt, T, N);
  hist_kernel<<<(E + 255) / 256, 256, 0, stream>>>(dstp, cnt, rank, E);
  scan1_kernel<<<nscan, 256, 0, stream>>>(cnt, offs, bsum, N);
  scan2_kernel<<<1, 64, 0, stream>>>(bsum, boffs, nscan, offs, N);
  scan3_kernel<<<nscan, 256, 0, stream>>>(offs, boffs, N);
  scatter_kernel<<<(E + 255) / 256, 256, 0, stream>>>(srcp, dstp, et, offs, rank, packed, E);
  gemm_kernel<<<mtiles, 256, 0, stream>>>(x, WcatT, biascat, Y, N, ncol, NB);
  agg_kernel<<<(N + 3) / 4, 256, 0, stream>>>(Y, offs, packed, out, N, T, 1.0f / (float)T, ncol);
}

// Round 5
// 309.701 us; speedup vs baseline: 1.0421x; 1.0421x over previous
//
#include <hip/hip_runtime.h>

typedef unsigned short u16;
typedef unsigned int u32;
typedef __attribute__((ext_vector_type(8))) short bf16x8;
typedef __attribute__((ext_vector_type(4))) float f32x4;
typedef __attribute__((ext_vector_type(2))) float f32x2;
typedef __attribute__((ext_vector_type(8))) u16 u16x8;
typedef __attribute__((ext_vector_type(4))) u16 u16x4;
typedef __attribute__((ext_vector_type(2))) u16 u16x2;
typedef __attribute__((ext_vector_type(2))) u32 u32x2;

#define DIM 128
#define AS1C(p) ((const __attribute__((address_space(1))) void*)(p))
#define AS3P(p) ((__attribute__((address_space(3))) void*)(p))

__device__ __forceinline__ u32 f2bf(float f){
  u32 x = __float_as_uint(f);
  return (x + 0x7fffu + ((x >> 16) & 1u)) >> 16;
}
__device__ __forceinline__ float bf2f(u16 u){
  return __uint_as_float(((u32)u) << 16);
}

// ---------------- prep: build W + cast x -> bf16 (padded) + zero cnt ---------
// W column layout (global col c, ncol = (3T+1)*128):
//   c in [0, 2T*128): per type t (256 cols): even -> Wq[t][:,j], odd -> Wv[t][:,j]
//   c in [2T*128, 3T*128): Wk[t][:,j]
//   c in [3T*128, ...): mean_t Ws[t][:,j]
__global__ __launch_bounds__(256) void prep_kernel(
    const float* __restrict__ x, u16* __restrict__ xb,
    const float* __restrict__ Wk, const float* __restrict__ bk,
    const float* __restrict__ Wq, const float* __restrict__ bq,
    const float* __restrict__ Wv, const float* __restrict__ bv,
    const float* __restrict__ Ws, const float* __restrict__ bb,
    u16* __restrict__ WcatT, float* __restrict__ biascat,
    int* __restrict__ cnt, int T, int N, int rows){
  int id = blockIdx.x * 256 + threadIdx.x;
  int total_w = (3 * T + 1) * DIM * DIM;
  int total_cast = rows * (DIM / 4);
  if (id >= total_w){
    int z = id - total_w;
    if (z < total_cast){
      int el = z * 4;
      int node = el >> 7;
      u32x2 pk;
      if (node < N){
        f32x4 v = *(const f32x4*)(x + el);
        pk.x = f2bf(v.x) | (f2bf(v.y) << 16);
        pk.y = f2bf(v.z) | (f2bf(v.w) << 16);
      } else { pk.x = 0u; pk.y = 0u; }
      *(u32x2*)(xb + el) = pk;
    } else {
      int z2 = z - total_cast;
      if (z2 < N) cnt[z2] = 0;
    }
    return;
  }
  int kk = id & (DIM - 1);
  int c  = id >> 7;
  int qvspan = 2 * T * DIM;
  float wv, bvv;
  if (c < qvspan){
    int t = c >> 8;
    int w = c & 255;
    int j = w >> 1;
    if ((w & 1) == 0){ wv = Wq[(t*DIM + kk)*DIM + j]; bvv = bq[t*DIM + j]; }
    else             { wv = Wv[(t*DIM + kk)*DIM + j]; bvv = bv[t*DIM + j]; }
  } else if (c < qvspan + T * DIM){
    int t = (c - qvspan) >> 7;
    int j = (c - qvspan) & (DIM - 1);
    wv = Wk[(t*DIM + kk)*DIM + j]; bvv = bk[t*DIM + j];
  } else {
    int j = c - 3 * T * DIM;
    float s = 0.f, sb = 0.f;
    for (int t = 0; t < T; ++t){ s += Ws[(t*DIM + kk)*DIM + j]; sb += bb[t*DIM + j]; }
    wv = s / (float)T; bvv = sb / (float)T;
  }
  WcatT[(size_t)c * DIM + kk] = (u16)f2bf(wv);
  if (kk == 0) biascat[c] = bvv;
}

// ---------------- CSR build --------------------------------------------------
__global__ __launch_bounds__(256) void hist_kernel(const int* __restrict__ dst,
                                                   int* __restrict__ cnt,
                                                   int* __restrict__ rank, int E){
  int e = blockIdx.x * 256 + threadIdx.x;
  if (e < E) rank[e] = atomicAdd(&cnt[dst[e]], 1);
}

// per-2048-chunk exclusive scan (offs holds chunk-local prefix; bsum = chunk sums)
__global__ __launch_bounds__(256) void scan1_kernel(const int* __restrict__ cnt,
                                                    int* __restrict__ offs,
                                                    int* __restrict__ bsum, int n){
  __shared__ int wsum[4];
  const int tid = threadIdx.x;
  const int lane = tid & 63, wave = tid >> 6;
  const int base = blockIdx.x * 2048 + tid * 8;
  int v[8]; int tot = 0;
#pragma unroll
  for (int j = 0; j < 8; ++j){
    int idx = base + j;
    int val = (idx < n) ? cnt[idx] : 0;
    v[j] = val; tot += val;
  }
  int incl = tot;
#pragma unroll
  for (int d = 1; d < 64; d <<= 1){
    int u = __shfl_up(incl, d, 64);
    if (lane >= d) incl += u;
  }
  if (lane == 63) wsum[wave] = incl;
  __syncthreads();
  int wbase = 0;
#pragma unroll
  for (int w = 0; w < 4; ++w) if (w < wave) wbase += wsum[w];
  int excl = wbase + incl - tot;
  if (tid == 255) bsum[blockIdx.x] = wbase + incl;
#pragma unroll
  for (int j = 0; j < 8; ++j){
    int idx = base + j;
    if (idx < n) offs[idx] = excl;
    excl += v[j];
  }
}

// exclusive scan of chunk sums -> boffs (nb <= 64)
__global__ __launch_bounds__(64) void scan2_kernel(const int* __restrict__ bsum,
                                                   int* __restrict__ boffs, int nb){
  int lane = threadIdx.x;
  int v = (lane < nb) ? bsum[lane] : 0;
  int incl = v;
#pragma unroll
  for (int d = 1; d < 64; d <<= 1){
    int u = __shfl_up(incl, d, 64);
    if (lane >= d) incl += u;
  }
  if (lane < nb) boffs[lane] = incl - v;
}

// pos = offs[d] + boffs[d>>11] + rank[e]  (scan3 folded in, no atomics)
__global__ __launch_bounds__(256) void scatter_kernel(const int* __restrict__ src,
                                                      const int* __restrict__ dst,
                                                      const int* __restrict__ et,
                                                      const int* __restrict__ offs,
                                                      const int* __restrict__ boffs,
                                                      const int* __restrict__ rank,
                                                      int* __restrict__ packed, int E){
  int e = blockIdx.x * 256 + threadIdx.x;
  if (e >= E) return;
  int d = dst[e];
  int pos = offs[d] + boffs[d >> 11] + rank[e];
  packed[pos] = (src[e] << 2) | (et[e] & 3);
}

// ---------------- GEMM: Y = xb @ Wcat + bias (bf16 out) ----------------------
// Full-K single-stage: both 128x128 bf16 tiles staged in one shot (64 KB LDS),
// ONE barrier pair per block. Grid (13 nt fastest, 391 mt) = 5083 blocks for
// deep queue (R4 lesson: queue depth, not per-block reuse, hides the drain).
// XOR swizzle: physical 8-elem block p of row r holds logical block p^(r&7).
// D mapping (A=W^T frag, B=x frag): col(=node)=lane&15, row(=feat)=quad*4+reg.
__global__ __launch_bounds__(256, 2) void gemm_kernel(const u16* __restrict__ xb,
                                                      const u16* __restrict__ WcatT,
                                                      const float* __restrict__ biascat,
                                                      u16* __restrict__ Y,
                                                      int N, int ncol){
  __shared__ u16 xt[DIM * DIM];   // 32 KB
  __shared__ u16 wt[DIM * DIM];   // 32 KB
  const int n0 = blockIdx.x * 128;
  const int m0 = blockIdx.y * 128;
  const int tid  = threadIdx.x;
  const int wave = tid >> 6;
  const int lane = tid & 63;
  const int l15  = lane & 15;
  const int quad = lane >> 4;
  const int wrow = wave * 32;

  // stage both full tiles (16 DMA issues per thread, one drain)
#pragma unroll
  for (int it = 0; it < 8; ++it){
    int s  = it * 256 + tid;
    int r  = s >> 4;
    int p  = s & 15;
    int lb = p ^ (r & 7);
    int lbase = (it * 256 + wave * 64) * 8;   // wave-uniform base, +lane*16B
    __builtin_amdgcn_global_load_lds(AS1C(xb + (size_t)(m0 + r) * DIM + lb * 8),
                                     AS3P(xt + lbase), 16, 0, 0);
    __builtin_amdgcn_global_load_lds(AS1C(WcatT + (size_t)(n0 + r) * DIM + lb * 8),
                                     AS3P(wt + lbase), 16, 0, 0);
  }
  __syncthreads();

  f32x4 acc[2][8];
#pragma unroll
  for (int mt = 0; mt < 2; ++mt)
#pragma unroll
    for (int nt = 0; nt < 8; ++nt)
      acc[mt][nt] = (f32x4){0.f, 0.f, 0.f, 0.f};

#pragma unroll
  for (int ks = 0; ks < 4; ++ks){
    const int pb8 = (((ks * 4 + quad) ^ (l15 & 7)) * 8);
    bf16x8 bfr[2], afr[8];
#pragma unroll
    for (int mt = 0; mt < 2; ++mt)
      bfr[mt] = *(const bf16x8*)&xt[(wrow + mt * 16 + l15) * DIM + pb8];
#pragma unroll
    for (int f = 0; f < 8; ++f)
      afr[f] = *(const bf16x8*)&wt[(f * 16 + l15) * DIM + pb8];
#pragma unroll
    for (int f = 0; f < 8; ++f)
#pragma unroll
      for (int mt = 0; mt < 2; ++mt)
        acc[mt][f] = __builtin_amdgcn_mfma_f32_16x16x32_bf16(afr[f], bfr[mt], acc[mt][f], 0, 0, 0);
  }

#pragma unroll
  for (int mt = 0; mt < 2; ++mt){
    int node = m0 + wrow + mt * 16 + l15;
    if (node >= N) continue;
    size_t rowbase = (size_t)node * ncol;
#pragma unroll
    for (int f = 0; f < 8; ++f){
      int feat = n0 + f * 16 + quad * 4;
      f32x4 b4 = *(const f32x4*)&biascat[feat];
      f32x4 v  = acc[mt][f];
      u32 lo = f2bf(v.x + b4.x) | (f2bf(v.y + b4.y) << 16);
      u32 hi = f2bf(v.z + b4.z) | (f2bf(v.w + b4.w) << 16);
      u32x2 pk = {lo, hi};
      *(u32x2*)&Y[rowbase + feat] = pk;
    }
  }
}

// ---------------- aggregate + epilogue: 2 nodes per wave (32 lanes each) -----
// One gather instr fetches TWO edges' 512B payloads (u16x8 per lane).
__global__ __launch_bounds__(256) void agg_kernel(const u16* __restrict__ Y,
                                                  const int* __restrict__ offs,
                                                  const int* __restrict__ boffs,
                                                  const int* __restrict__ packed,
                                                  float* __restrict__ out,
                                                  int N, int E, float invT, int ncol){
  const int wave = threadIdx.x >> 6;
  const int lane = threadIdx.x & 63;
  const int half = lane >> 5;
  const int l32  = lane & 31;
  const int node = blockIdx.x * 8 + wave * 2 + half;
  const bool valid = node < N;
  const int nc = valid ? node : N - 1;

  const int kqoff = 1024;   // 2*T*DIM
  const int soff  = 1536;   // 3*T*DIM
  const u16* yr = Y + (size_t)nc * ncol;
  const int c4 = l32 * 4;

  // per-lane 4 feats of k (per type) and s
  u16x4 kw[4];
#pragma unroll
  for (int t = 0; t < 4; ++t)
    kw[t] = *(const u16x4*)(yr + kqoff + t * DIM + c4);
  u16x4 sw = *(const u16x4*)(yr + soff + c4);

  int e0 = 0, e1 = 0;
  if (valid){
    e0 = offs[nc] + boffs[nc >> 11];
    e1 = (nc == N - 1) ? E : (offs[nc + 1] + boffs[(nc + 1) >> 11]);
  }

  f32x4 acc = {0.f, 0.f, 0.f, 0.f};
  int e = e0;
  for (; e + 4 <= e1; e += 4){
    int p[4];
#pragma unroll
    for (int j = 0; j < 4; ++j) p[j] = packed[e + j];
    u16x8 a[4];
#pragma unroll
    for (int j = 0; j < 4; ++j)
      a[j] = *(const u16x8*)(Y + (size_t)(p[j] >> 2) * ncol + (p[j] & 3) * 256 + l32 * 8);
#pragma unroll
    for (int j = 0; j < 4; ++j){
      int t = p[j] & 3;
      u16x4 kwt = (t == 0) ? kw[0] : (t == 1) ? kw[1] : (t == 2) ? kw[2] : kw[3];
      acc.x += bf2f(a[j].s1) * __builtin_amdgcn_rcpf(1.f + __expf(-(bf2f(kwt.x) + bf2f(a[j].s0))));
      acc.y += bf2f(a[j].s3) * __builtin_amdgcn_rcpf(1.f + __expf(-(bf2f(kwt.y) + bf2f(a[j].s2))));
      acc.z += bf2f(a[j].s5) * __builtin_amdgcn_rcpf(1.f + __expf(-(bf2f(kwt.z) + bf2f(a[j].s4))));
      acc.w += bf2f(a[j].s7) * __builtin_amdgcn_rcpf(1.f + __expf(-(bf2f(kwt.w) + bf2f(a[j].s6))));
    }
  }
  for (; e < e1; ++e){
    int p = packed[e];
    int t = p & 3;
    u16x8 a = *(const u16x8*)(Y + (size_t)(p >> 2) * ncol + t * 256 + l32 * 8);
    u16x4 kwt = (t == 0) ? kw[0] : (t == 1) ? kw[1] : (t == 2) ? kw[2] : kw[3];
    acc.x += bf2f(a.s1) * __builtin_amdgcn_rcpf(1.f + __expf(-(bf2f(kwt.x) + bf2f(a.s0))));
    acc.y += bf2f(a.s3) * __builtin_amdgcn_rcpf(1.f + __expf(-(bf2f(kwt.y) + bf2f(a.s2))));
    acc.z += bf2f(a.s5) * __builtin_amdgcn_rcpf(1.f + __expf(-(bf2f(kwt.z) + bf2f(a.s4))));
    acc.w += bf2f(a.s7) * __builtin_amdgcn_rcpf(1.f + __expf(-(bf2f(kwt.w) + bf2f(a.s6))));
  }
  if (valid){
    f32x4 o = { invT * acc.x + bf2f(sw.x), invT * acc.y + bf2f(sw.y),
                invT * acc.z + bf2f(sw.z), invT * acc.w + bf2f(sw.w) };
    *(f32x4*)&out[(size_t)node * DIM + c4] = o;
  }
}

// ---------------- launch -----------------------------------------------------
extern "C" void kernel_launch(void* const* d_in, const int* in_sizes, int n_in,
                              void* d_out, int out_size, void* d_ws, size_t ws_size,
                              hipStream_t stream){
  const float* x  = (const float*)d_in[0];
  const int*   ei = (const int*)d_in[1];
  const int*   et = (const int*)d_in[2];
  const float* Wk = (const float*)d_in[3];
  const float* bk = (const float*)d_in[4];
  const float* Wq = (const float*)d_in[5];
  const float* bq = (const float*)d_in[6];
  const float* Wv = (const float*)d_in[7];
  const float* bv = (const float*)d_in[8];
  const float* Ws = (const float*)d_in[9];
  const float* bb = (const float*)d_in[10];
  float* out = (float*)d_out;

  const int N = in_sizes[0] / DIM;
  const int E = in_sizes[2];
  const int T = in_sizes[3] / (DIM * DIM);
  const int NB = 3 * T + 1;
  const int ncol = NB * DIM;
  const int mtiles = (N + 127) / 128;
  const int rows = mtiles * 128;
  const int nscan = (N + 2047) / 2048;

  char* ws = (char*)d_ws;
  size_t off = 0;
  auto alloc = [&](size_t bytes) -> char* {
    char* p = ws + off;
    off = (off + bytes + 255) & ~(size_t)255;
    return p;
  };
  u16*   xb      = (u16*)alloc((size_t)rows * DIM * 2);
  u16*   WcatT   = (u16*)alloc((size_t)ncol * DIM * 2);
  float* biascat = (float*)alloc((size_t)ncol * 4);
  u16*   Y       = (u16*)alloc((size_t)N * ncol * 2);
  int*   cnt     = (int*)alloc((size_t)N * 4);
  int*   offs    = (int*)alloc((size_t)N * 4);
  int*   rank    = (int*)alloc((size_t)E * 4);
  int*   packed  = (int*)alloc((size_t)E * 4);
  int*   bsum    = (int*)alloc((size_t)nscan * 4);
  int*   boffs   = (int*)alloc((size_t)nscan * 4);
  (void)ws_size; (void)n_in; (void)out_size;

  const int* srcp = ei;
  const int* dstp = ei + E;

  int prep_total = NB * DIM * DIM + rows * (DIM / 4) + N;
  prep_kernel<<<(prep_total + 255) / 256, 256, 0, stream>>>(x, xb, Wk, bk, Wq, bq, Wv, bv,
                                                            Ws, bb, WcatT, biascat, cnt, T, N, rows);
  hist_kernel<<<(E + 255) / 256, 256, 0, stream>>>(dstp, cnt, rank, E);
  scan1_kernel<<<nscan, 256, 0, stream>>>(cnt, offs, bsum, N);
  scan2_kernel<<<1, 64, 0, stream>>>(bsum, boffs, nscan);
  scatter_kernel<<<(E + 255) / 256, 256, 0, stream>>>(srcp, dstp, et, offs, boffs, rank, packed, E);
  dim3 g(NB, mtiles);
  gemm_kernel<<<g, 256, 0, stream>>>(xb, WcatT, biascat, Y, N, ncol);
  agg_kernel<<<(N + 7) / 8, 256, 0, stream>>>(Y, offs, boffs, packed, out, N, E, 1.0f / (float)T, ncol);
}

// Round 6
// 306.097 us; speedup vs baseline: 1.0544x; 1.0118x over previous
//
#include <hip/hip_runtime.h>

typedef unsigned short u16;
typedef unsigned int u32;
typedef __attribute__((ext_vector_type(8))) short bf16x8;
typedef __attribute__((ext_vector_type(4))) float f32x4;
typedef __attribute__((ext_vector_type(2))) float f32x2;
typedef __attribute__((ext_vector_type(8))) u16 u16x8;
typedef __attribute__((ext_vector_type(4))) u16 u16x4;
typedef __attribute__((ext_vector_type(2))) u16 u16x2;
typedef __attribute__((ext_vector_type(2))) u32 u32x2;

#define DIM 128
#define AS1C(p) ((const __attribute__((address_space(1))) void*)(p))
#define AS3P(p) ((__attribute__((address_space(3))) void*)(p))

__device__ __forceinline__ u32 f2bf(float f){
  u32 x = __float_as_uint(f);
  return (x + 0x7fffu + ((x >> 16) & 1u)) >> 16;
}
__device__ __forceinline__ float bf2f(u16 u){
  return __uint_as_float(((u32)u) << 16);
}

// ---------------- prep: build W + cast x -> bf16 (padded) + zero cnt ---------
// W column layout (global col c, ncol = (3T+1)*128):
//   c in [0, 2T*128): per type t (256 cols): even -> Wq[t][:,j], odd -> Wv[t][:,j]
//   c in [2T*128, 3T*128): Wk[t][:,j]
//   c in [3T*128, ...): mean_t Ws[t][:,j]
__global__ __launch_bounds__(256) void prep_kernel(
    const float* __restrict__ x, u16* __restrict__ xb,
    const float* __restrict__ Wk, const float* __restrict__ bk,
    const float* __restrict__ Wq, const float* __restrict__ bq,
    const float* __restrict__ Wv, const float* __restrict__ bv,
    const float* __restrict__ Ws, const float* __restrict__ bb,
    u16* __restrict__ WcatT, float* __restrict__ biascat,
    int* __restrict__ cnt, int T, int N, int rows){
  int id = blockIdx.x * 256 + threadIdx.x;
  int total_w = (3 * T + 1) * DIM * DIM;
  int total_cast = rows * (DIM / 4);
  if (id >= total_w){
    int z = id - total_w;
    if (z < total_cast){
      int el = z * 4;
      int node = el >> 7;
      u32x2 pk;
      if (node < N){
        f32x4 v = *(const f32x4*)(x + el);
        pk.x = f2bf(v.x) | (f2bf(v.y) << 16);
        pk.y = f2bf(v.z) | (f2bf(v.w) << 16);
      } else { pk.x = 0u; pk.y = 0u; }
      *(u32x2*)(xb + el) = pk;
    } else {
      int z2 = z - total_cast;
      if (z2 < N) cnt[z2] = 0;
    }
    return;
  }
  int kk = id & (DIM - 1);
  int c  = id >> 7;
  int qvspan = 2 * T * DIM;
  float wv, bvv;
  if (c < qvspan){
    int t = c >> 8;
    int w = c & 255;
    int j = w >> 1;
    if ((w & 1) == 0){ wv = Wq[(t*DIM + kk)*DIM + j]; bvv = bq[t*DIM + j]; }
    else             { wv = Wv[(t*DIM + kk)*DIM + j]; bvv = bv[t*DIM + j]; }
  } else if (c < qvspan + T * DIM){
    int t = (c - qvspan) >> 7;
    int j = (c - qvspan) & (DIM - 1);
    wv = Wk[(t*DIM + kk)*DIM + j]; bvv = bk[t*DIM + j];
  } else {
    int j = c - 3 * T * DIM;
    float s = 0.f, sb = 0.f;
    for (int t = 0; t < T; ++t){ s += Ws[(t*DIM + kk)*DIM + j]; sb += bb[t*DIM + j]; }
    wv = s / (float)T; bvv = sb / (float)T;
  }
  WcatT[(size_t)c * DIM + kk] = (u16)f2bf(wv);
  if (kk == 0) biascat[c] = bvv;
}

// ---------------- CSR build --------------------------------------------------
__global__ __launch_bounds__(256) void hist_kernel(const int* __restrict__ dst,
                                                   int* __restrict__ cnt,
                                                   int* __restrict__ rank, int E){
  int e = blockIdx.x * 256 + threadIdx.x;
  if (e < E) rank[e] = atomicAdd(&cnt[dst[e]], 1);
}

// per-2048-chunk exclusive scan (offs holds chunk-local prefix; bsum = chunk sums)
__global__ __launch_bounds__(256) void scan1_kernel(const int* __restrict__ cnt,
                                                    int* __restrict__ offs,
                                                    int* __restrict__ bsum, int n){
  __shared__ int wsum[4];
  const int tid = threadIdx.x;
  const int lane = tid & 63, wave = tid >> 6;
  const int base = blockIdx.x * 2048 + tid * 8;
  int v[8]; int tot = 0;
#pragma unroll
  for (int j = 0; j < 8; ++j){
    int idx = base + j;
    int val = (idx < n) ? cnt[idx] : 0;
    v[j] = val; tot += val;
  }
  int incl = tot;
#pragma unroll
  for (int d = 1; d < 64; d <<= 1){
    int u = __shfl_up(incl, d, 64);
    if (lane >= d) incl += u;
  }
  if (lane == 63) wsum[wave] = incl;
  __syncthreads();
  int wbase = 0;
#pragma unroll
  for (int w = 0; w < 4; ++w) if (w < wave) wbase += wsum[w];
  int excl = wbase + incl - tot;
  if (tid == 255) bsum[blockIdx.x] = wbase + incl;
#pragma unroll
  for (int j = 0; j < 8; ++j){
    int idx = base + j;
    if (idx < n) offs[idx] = excl;
    excl += v[j];
  }
}

// exclusive scan of chunk sums -> boffs (nb <= 64)
__global__ __launch_bounds__(64) void scan2_kernel(const int* __restrict__ bsum,
                                                   int* __restrict__ boffs, int nb){
  int lane = threadIdx.x;
  int v = (lane < nb) ? bsum[lane] : 0;
  int incl = v;
#pragma unroll
  for (int d = 1; d < 64; d <<= 1){
    int u = __shfl_up(incl, d, 64);
    if (lane >= d) incl += u;
  }
  if (lane < nb) boffs[lane] = incl - v;
}

// pos = offs[d] + boffs[d>>11] + rank[e]  (no atomics)
__global__ __launch_bounds__(256) void scatter_kernel(const int* __restrict__ src,
                                                      const int* __restrict__ dst,
                                                      const int* __restrict__ et,
                                                      const int* __restrict__ offs,
                                                      const int* __restrict__ boffs,
                                                      const int* __restrict__ rank,
                                                      int* __restrict__ packed, int E){
  int e = blockIdx.x * 256 + threadIdx.x;
  if (e >= E) return;
  int d = dst[e];
  int pos = offs[d] + boffs[d >> 11] + rank[e];
  packed[pos] = (src[e] << 2) | (et[e] & 3);
}

// ---------------- GEMM: Y = xb @ Wcat + bias (bf16 out) ----------------------
// W-tile (32 KB) in LDS (shared by 4 waves, XOR-swizzled, global_load_lds w16);
// x fragments streamed global->VGPR (each wave reads only its own 32 nodes;
// loads issued before the DMA drain so their latency hides under it).
// 4 blocks/CU (32 KB LDS, launch_bounds(256,4)) for drain overlap.
// Block swizzle: groups of 8 consecutive blocks = 8 m-tiles (one per XCD),
// nt cycles fastest within a group-column -> x-tile stays hot per XCD.
// D mapping (A=W^T frag, B=x frag): col(=node)=lane&15, row(=feat)=quad*4+reg.
__global__ __launch_bounds__(256, 4) void gemm_kernel(const u16* __restrict__ xb,
                                                      const u16* __restrict__ WcatT,
                                                      const float* __restrict__ biascat,
                                                      u16* __restrict__ Y,
                                                      int N, int ncol, int NB, int mtiles){
  __shared__ u16 wt[DIM * DIM];   // 32 KB
  int bid = blockIdx.x;
  int body = NB * (mtiles & ~7);
  int mt, nt;
  if (bid < body){
    int g = bid >> 3, r = bid & 7;
    int a = g / NB;
    mt = a * 8 + r;
    nt = g - a * NB;
  } else {
    int z = bid - body;
    mt = (mtiles & ~7) + z / NB;
    nt = z % NB;
  }
  const int m0 = mt * 128;
  const int n0 = nt * 128;
  const int tid  = threadIdx.x;
  const int wave = tid >> 6;
  const int lane = tid & 63;
  const int l15  = lane & 15;
  const int quad = lane >> 4;
  const int wrow = wave * 32;

  // x fragment base: node row = m0 + wrow + mtt*16 + l15, k = ks*32 + quad*8
  const u16* xrow0 = xb + (size_t)(m0 + wrow + l15) * DIM + quad * 8;
  const u16* xrow1 = xrow0 + 16 * DIM;

  // prefetch x for ks=0,1 (independent of LDS barrier)
  bf16x8 bcur[2], bnxt[2];
  bcur[0] = *(const bf16x8*)(xrow0 + 0);
  bcur[1] = *(const bf16x8*)(xrow1 + 0);
  bnxt[0] = *(const bf16x8*)(xrow0 + 32);
  bnxt[1] = *(const bf16x8*)(xrow1 + 32);

  // stage W tile (8 DMA issues/thread), XOR swizzle: phys block p of row r
  // holds logical block p^(r&7)
#pragma unroll
  for (int it = 0; it < 8; ++it){
    int s  = it * 256 + tid;
    int r  = s >> 4;
    int p  = s & 15;
    int lb = p ^ (r & 7);
    int lbase = (it * 256 + wave * 64) * 8;   // wave-uniform base, +lane*16B
    __builtin_amdgcn_global_load_lds(AS1C(WcatT + (size_t)(n0 + r) * DIM + lb * 8),
                                     AS3P(wt + lbase), 16, 0, 0);
  }
  __syncthreads();

  f32x4 acc[2][8];
#pragma unroll
  for (int m = 0; m < 2; ++m)
#pragma unroll
    for (int f = 0; f < 8; ++f)
      acc[m][f] = (f32x4){0.f, 0.f, 0.f, 0.f};

#pragma unroll
  for (int ks = 0; ks < 4; ++ks){
    bf16x8 b0 = bcur[0], b1 = bcur[1];
    if (ks < 3){
      bcur[0] = bnxt[0]; bcur[1] = bnxt[1];
      if (ks < 2){
        bnxt[0] = *(const bf16x8*)(xrow0 + (ks + 2) * 32);
        bnxt[1] = *(const bf16x8*)(xrow1 + (ks + 2) * 32);
      }
    }
    const int pb8 = (((ks * 4 + quad) ^ (l15 & 7)) * 8);
#pragma unroll
    for (int f = 0; f < 8; ++f){
      bf16x8 afr = *(const bf16x8*)&wt[(f * 16 + l15) * DIM + pb8];
      acc[0][f] = __builtin_amdgcn_mfma_f32_16x16x32_bf16(afr, b0, acc[0][f], 0, 0, 0);
      acc[1][f] = __builtin_amdgcn_mfma_f32_16x16x32_bf16(afr, b1, acc[1][f], 0, 0, 0);
    }
  }

#pragma unroll
  for (int m = 0; m < 2; ++m){
    int node = m0 + wrow + m * 16 + l15;
    if (node >= N) continue;
    size_t rowbase = (size_t)node * ncol;
#pragma unroll
    for (int f = 0; f < 8; ++f){
      int feat = n0 + f * 16 + quad * 4;
      f32x4 b4 = *(const f32x4*)&biascat[feat];
      f32x4 v  = acc[m][f];
      u32 lo = f2bf(v.x + b4.x) | (f2bf(v.y + b4.y) << 16);
      u32 hi = f2bf(v.z + b4.z) | (f2bf(v.w + b4.w) << 16);
      u32x2 pk = {lo, hi};
      *(u32x2*)&Y[rowbase + feat] = pk;
    }
  }
}

// ---------------- aggregate + epilogue: 2 nodes per wave (32 lanes each) -----
// One gather instr fetches TWO edges' 512B payloads; unroll 8 for deep MLP.
__global__ __launch_bounds__(256) void agg_kernel(const u16* __restrict__ Y,
                                                  const int* __restrict__ offs,
                                                  const int* __restrict__ boffs,
                                                  const int* __restrict__ packed,
                                                  float* __restrict__ out,
                                                  int N, int E, float invT, int ncol){
  const int wave = threadIdx.x >> 6;
  const int lane = threadIdx.x & 63;
  const int half = lane >> 5;
  const int l32  = lane & 31;
  const int node = blockIdx.x * 8 + wave * 2 + half;
  const bool valid = node < N;
  const int nc = valid ? node : N - 1;

  const int kqoff = 1024;   // 2*T*DIM
  const int soff  = 1536;   // 3*T*DIM
  const u16* yr = Y + (size_t)nc * ncol;
  const int c4 = l32 * 4;

  u16x4 kw[4];
#pragma unroll
  for (int t = 0; t < 4; ++t)
    kw[t] = *(const u16x4*)(yr + kqoff + t * DIM + c4);
  u16x4 sw = *(const u16x4*)(yr + soff + c4);

  int e0 = 0, e1 = 0;
  if (valid){
    e0 = offs[nc] + boffs[nc >> 11];
    e1 = (nc == N - 1) ? E : (offs[nc + 1] + boffs[(nc + 1) >> 11]);
  }

  f32x4 acc = {0.f, 0.f, 0.f, 0.f};
  int e = e0;
  for (; e + 8 <= e1; e += 8){
    int p[8];
#pragma unroll
    for (int j = 0; j < 8; ++j) p[j] = packed[e + j];
    u16x8 a[8];
#pragma unroll
    for (int j = 0; j < 8; ++j)
      a[j] = *(const u16x8*)(Y + (size_t)(p[j] >> 2) * ncol + (p[j] & 3) * 256 + l32 * 8);
#pragma unroll
    for (int j = 0; j < 8; ++j){
      int t = p[j] & 3;
      u16x4 kwt = (t == 0) ? kw[0] : (t == 1) ? kw[1] : (t == 2) ? kw[2] : kw[3];
      acc.x += bf2f(a[j].s1) * __builtin_amdgcn_rcpf(1.f + __expf(-(bf2f(kwt.x) + bf2f(a[j].s0))));
      acc.y += bf2f(a[j].s3) * __builtin_amdgcn_rcpf(1.f + __expf(-(bf2f(kwt.y) + bf2f(a[j].s2))));
      acc.z += bf2f(a[j].s5) * __builtin_amdgcn_rcpf(1.f + __expf(-(bf2f(kwt.z) + bf2f(a[j].s4))));
      acc.w += bf2f(a[j].s7) * __builtin_amdgcn_rcpf(1.f + __expf(-(bf2f(kwt.w) + bf2f(a[j].s6))));
    }
  }
  for (; e < e1; ++e){
    int p = packed[e];
    int t = p & 3;
    u16x8 a = *(const u16x8*)(Y + (size_t)(p >> 2) * ncol + t * 256 + l32 * 8);
    u16x4 kwt = (t == 0) ? kw[0] : (t == 1) ? kw[1] : (t == 2) ? kw[2] : kw[3];
    acc.x += bf2f(a.s1) * __builtin_amdgcn_rcpf(1.f + __expf(-(bf2f(kwt.x) + bf2f(a.s0))));
    acc.y += bf2f(a.s3) * __builtin_amdgcn_rcpf(1.f + __expf(-(bf2f(kwt.y) + bf2f(a.s2))));
    acc.z += bf2f(a.s5) * __builtin_amdgcn_rcpf(1.f + __expf(-(bf2f(kwt.z) + bf2f(a.s4))));
    acc.w += bf2f(a.s7) * __builtin_amdgcn_rcpf(1.f + __expf(-(bf2f(kwt.w) + bf2f(a.s6))));
  }
  if (valid){
    f32x4 o = { invT * acc.x + bf2f(sw.x), invT * acc.y + bf2f(sw.y),
                invT * acc.z + bf2f(sw.z), invT * acc.w + bf2f(sw.w) };
    *(f32x4*)&out[(size_t)node * DIM + c4] = o;
  }
}

// ---------------- launch -----------------------------------------------------
extern "C" void kernel_launch(void* const* d_in, const int* in_sizes, int n_in,
                              void* d_out, int out_size, void* d_ws, size_t ws_size,
                              hipStream_t stream){
  const float* x  = (const float*)d_in[0];
  const int*   ei = (const int*)d_in[1];
  const int*   et = (const int*)d_in[2];
  const float* Wk = (const float*)d_in[3];
  const float* bk = (const float*)d_in[4];
  const float* Wq = (const float*)d_in[5];
  const float* bq = (const float*)d_in[6];
  const float* Wv = (const float*)d_in[7];
  const float* bv = (const float*)d_in[8];
  const float* Ws = (const float*)d_in[9];
  const float* bb = (const float*)d_in[10];
  float* out = (float*)d_out;

  const int N = in_sizes[0] / DIM;
  const int E = in_sizes[2];
  const int T = in_sizes[3] / (DIM * DIM);
  const int NB = 3 * T + 1;
  const int ncol = NB * DIM;
  const int mtiles = (N + 127) / 128;
  const int rows = mtiles * 128;
  const int nscan = (N + 2047) / 2048;

  char* ws = (char*)d_ws;
  size_t off = 0;
  auto alloc = [&](size_t bytes) -> char* {
    char* p = ws + off;
    off = (off + bytes + 255) & ~(size_t)255;
    return p;
  };
  u16*   xb      = (u16*)alloc((size_t)rows * DIM * 2);
  u16*   WcatT   = (u16*)alloc((size_t)ncol * DIM * 2);
  float* biascat = (float*)alloc((size_t)ncol * 4);
  u16*   Y       = (u16*)alloc((size_t)N * ncol * 2);
  int*   cnt     = (int*)alloc((size_t)N * 4);
  int*   offs    = (int*)alloc((size_t)N * 4);
  int*   rank    = (int*)alloc((size_t)E * 4);
  int*   packed  = (int*)alloc((size_t)E * 4);
  int*   bsum    = (int*)alloc((size_t)nscan * 4);
  int*   boffs   = (int*)alloc((size_t)nscan * 4);
  (void)ws_size; (void)n_in; (void)out_size;

  const int* srcp = ei;
  const int* dstp = ei + E;

  int prep_total = NB * DIM * DIM + rows * (DIM / 4) + N;
  prep_kernel<<<(prep_total + 255) / 256, 256, 0, stream>>>(x, xb, Wk, bk, Wq, bq, Wv, bv,
                                                            Ws, bb, WcatT, biascat, cnt, T, N, rows);
  hist_kernel<<<(E + 255) / 256, 256, 0, stream>>>(dstp, cnt, rank, E);
  scan1_kernel<<<nscan, 256, 0, stream>>>(cnt, offs, bsum, N);
  scan2_kernel<<<1, 64, 0, stream>>>(bsum, boffs, nscan);
  scatter_kernel<<<(E + 255) / 256, 256, 0, stream>>>(srcp, dstp, et, offs, boffs, rank, packed, E);
  gemm_kernel<<<NB * mtiles, 256, 0, stream>>>(xb, WcatT, biascat, Y, N, ncol, NB, mtiles);
  agg_kernel<<<(N + 7) / 8, 256, 0, stream>>>(Y, offs, boffs, packed, out, N, E, 1.0f / (float)T, ncol);
}

// Round 7
// 289.698 us; speedup vs baseline: 1.1141x; 1.0566x over previous
//
#include <hip/hip_runtime.h>

typedef unsigned short u16;
typedef unsigned int u32;
typedef __attribute__((ext_vector_type(8))) short bf16x8;
typedef __attribute__((ext_vector_type(4))) float f32x4;
typedef __attribute__((ext_vector_type(8))) u16 u16x8;
typedef __attribute__((ext_vector_type(4))) u16 u16x4;
typedef __attribute__((ext_vector_type(2))) u32 u32x2;

#define DIM 128
// Y row layout (T=4): per type t: [q fp8 x128 | v bf16 x128] (384 B) at t*384;
// k bf16 4x256 B at 1536; s bf16 256 B at 2560. Row = 2816 B (22 cache lines).
#define ROWB 2816
#define QV_SPAN 384
#define K_OFF 1536
#define S_OFF 2560
#define AS1C(p) ((const __attribute__((address_space(1))) void*)(p))
#define AS3P(p) ((__attribute__((address_space(3))) void*)(p))

__device__ __forceinline__ u32 f2bf(float f){
  u32 x = __float_as_uint(f);
  return (x + 0x7fffu + ((x >> 16) & 1u)) >> 16;
}
__device__ __forceinline__ float bf2f(u16 u){
  return __uint_as_float(((u32)u) << 16);
}

// ------- prep: hist + build W (bf16,transposed,concat) + cast x->bf16 --------
// Wcat tile layout (13 tiles of 128 cols): nt<4: Wq[nt] (fp8 out);
// nt in 4..7: Wv[nt-4]; nt in 8..11: Wk[nt-8]; nt=12: mean_t Ws.
__global__ __launch_bounds__(256) void prep_kernel(
    const float* __restrict__ x, u16* __restrict__ xb,
    const int* __restrict__ dst, int* __restrict__ cnt, int* __restrict__ rank,
    const float* __restrict__ Wk, const float* __restrict__ bk,
    const float* __restrict__ Wq, const float* __restrict__ bq,
    const float* __restrict__ Wv, const float* __restrict__ bv,
    const float* __restrict__ Ws, const float* __restrict__ bb,
    u16* __restrict__ WcatT, float* __restrict__ biascat,
    int T, int N, int E, int rows){
  int id = blockIdx.x * 256 + threadIdx.x;
  if (id < E){                     // histogram + rank
    rank[id] = atomicAdd(&cnt[dst[id]], 1);
    return;
  }
  id -= E;
  int total_w = (3 * T + 1) * DIM * DIM;
  if (id < total_w){               // weight build
    int kk = id & (DIM - 1);
    int c  = id >> 7;
    int nt = c >> 7;
    int j  = c & (DIM - 1);
    float wv, bvv;
    if (nt < T)          { wv = Wq[(nt*DIM + kk)*DIM + j];      bvv = bq[nt*DIM + j]; }
    else if (nt < 2*T)   { wv = Wv[((nt-T)*DIM + kk)*DIM + j];  bvv = bv[(nt-T)*DIM + j]; }
    else if (nt < 3*T)   { wv = Wk[((nt-2*T)*DIM + kk)*DIM + j];bvv = bk[(nt-2*T)*DIM + j]; }
    else {
      float s = 0.f, sb = 0.f;
      for (int t = 0; t < T; ++t){ s += Ws[(t*DIM + kk)*DIM + j]; sb += bb[t*DIM + j]; }
      wv = s / (float)T; bvv = sb / (float)T;
    }
    WcatT[(size_t)c * DIM + kk] = (u16)f2bf(wv);
    if (kk == 0) biascat[c] = bvv;
    return;
  }
  id -= total_w;
  int total_cast = rows * (DIM / 4);
  if (id < total_cast){            // x -> bf16 (zero-padded rows)
    int el = id * 4;
    int node = el >> 7;
    u32x2 pk;
    if (node < N){
      f32x4 v = *(const f32x4*)(x + el);
      pk.x = f2bf(v.x) | (f2bf(v.y) << 16);
      pk.y = f2bf(v.z) | (f2bf(v.w) << 16);
    } else { pk.x = 0u; pk.y = 0u; }
    *(u32x2*)(xb + el) = pk;
  }
}

// per-2048-chunk exclusive scan (offs chunk-local; bsum = chunk totals)
__global__ __launch_bounds__(256) void scan1_kernel(const int* __restrict__ cnt,
                                                    int* __restrict__ offs,
                                                    int* __restrict__ bsum, int n){
  __shared__ int wsum[4];
  const int tid = threadIdx.x;
  const int lane = tid & 63, wave = tid >> 6;
  const int base = blockIdx.x * 2048 + tid * 8;
  int v[8]; int tot = 0;
#pragma unroll
  for (int j = 0; j < 8; ++j){
    int idx = base + j;
    int val = (idx < n) ? cnt[idx] : 0;
    v[j] = val; tot += val;
  }
  int incl = tot;
#pragma unroll
  for (int d = 1; d < 64; d <<= 1){
    int u = __shfl_up(incl, d, 64);
    if (lane >= d) incl += u;
  }
  if (lane == 63) wsum[wave] = incl;
  __syncthreads();
  int wbase = 0;
#pragma unroll
  for (int w = 0; w < 4; ++w) if (w < wave) wbase += wsum[w];
  int excl = wbase + incl - tot;
  if (tid == 255) bsum[blockIdx.x] = wbase + incl;
#pragma unroll
  for (int j = 0; j < 8; ++j){
    int idx = base + j;
    if (idx < n) offs[idx] = excl;
    excl += v[j];
  }
}

// exclusive scan of chunk sums (nb <= 64)
__global__ __launch_bounds__(64) void scan2_kernel(const int* __restrict__ bsum,
                                                   int* __restrict__ boffs, int nb){
  int lane = threadIdx.x;
  int v = (lane < nb) ? bsum[lane] : 0;
  int incl = v;
#pragma unroll
  for (int d = 1; d < 64; d <<= 1){
    int u = __shfl_up(incl, d, 64);
    if (lane >= d) incl += u;
  }
  if (lane < nb) boffs[lane] = incl - v;
}

// ---------------- fused scatter + GEMM ---------------------------------------
// Blocks [0, nsc): scatter packed[] (no atomics: offs+boffs+rank).
// Blocks [nsc, ...): GEMM Y = xb @ Wcat + bias with mixed fp8/bf16 output.
// W-tile (32 KB) LDS, XOR-swizzled, global_load_lds w16; x frags global->VGPR.
// XCD swizzle: groups of 8 blocks = 8 m-tiles; nt cycles fastest per group-col.
// D mapping (A=W^T frag, B=x frag): col(=node)=lane&15, row(=feat)=quad*4+reg.
__global__ __launch_bounds__(256, 4) void gemm_scatter_kernel(
    const u16* __restrict__ xb, const u16* __restrict__ WcatT,
    const float* __restrict__ biascat, char* __restrict__ Y,
    const int* __restrict__ src, const int* __restrict__ dst,
    const int* __restrict__ et, const int* __restrict__ offs,
    const int* __restrict__ boffs, const int* __restrict__ rank,
    int* __restrict__ packed,
    int N, int E, int T, int NB, int mtiles, int nsc){
  __shared__ u16 wt[DIM * DIM];   // 32 KB
  int bid = blockIdx.x;
  if (bid < nsc){
    int e = bid * 256 + threadIdx.x;
    if (e < E){
      int d = dst[e];
      int pos = offs[d] + boffs[d >> 11] + rank[e];
      packed[pos] = (src[e] << 2) | (et[e] & 3);
    }
    return;
  }
  bid -= nsc;
  int body = NB * (mtiles & ~7);
  int mt, nt;
  if (bid < body){
    int g = bid >> 3, r = bid & 7;
    int a = g / NB;
    mt = a * 8 + r;
    nt = g - a * NB;
  } else {
    int z = bid - body;
    mt = (mtiles & ~7) + z / NB;
    nt = z % NB;
  }
  const int m0 = mt * 128;
  const int n0 = nt * 128;
  const int tid  = threadIdx.x;
  const int wave = tid >> 6;
  const int lane = tid & 63;
  const int l15  = lane & 15;
  const int quad = lane >> 4;
  const int wrow = wave * 32;

  const u16* xrow0 = xb + (size_t)(m0 + wrow + l15) * DIM + quad * 8;
  const u16* xrow1 = xrow0 + 16 * DIM;

  bf16x8 bcur[2], bnxt[2];
  bcur[0] = *(const bf16x8*)(xrow0 + 0);
  bcur[1] = *(const bf16x8*)(xrow1 + 0);
  bnxt[0] = *(const bf16x8*)(xrow0 + 32);
  bnxt[1] = *(const bf16x8*)(xrow1 + 32);

  // stage W tile, XOR swizzle: phys block p of row r holds logical p^(r&7)
#pragma unroll
  for (int it = 0; it < 8; ++it){
    int s  = it * 256 + tid;
    int r  = s >> 4;
    int p  = s & 15;
    int lb = p ^ (r & 7);
    int lbase = (it * 256 + wave * 64) * 8;
    __builtin_amdgcn_global_load_lds(AS1C(WcatT + (size_t)(n0 + r) * DIM + lb * 8),
                                     AS3P(wt + lbase), 16, 0, 0);
  }
  __syncthreads();

  f32x4 acc[2][8];
#pragma unroll
  for (int m = 0; m < 2; ++m)
#pragma unroll
    for (int f = 0; f < 8; ++f)
      acc[m][f] = (f32x4){0.f, 0.f, 0.f, 0.f};

#pragma unroll
  for (int ks = 0; ks < 4; ++ks){
    bf16x8 b0 = bcur[0], b1 = bcur[1];
    if (ks < 3){
      bcur[0] = bnxt[0]; bcur[1] = bnxt[1];
      if (ks < 2){
        bnxt[0] = *(const bf16x8*)(xrow0 + (ks + 2) * 32);
        bnxt[1] = *(const bf16x8*)(xrow1 + (ks + 2) * 32);
      }
    }
    const int pb8 = (((ks * 4 + quad) ^ (l15 & 7)) * 8);
#pragma unroll
    for (int f = 0; f < 8; ++f){
      bf16x8 afr = *(const bf16x8*)&wt[(f * 16 + l15) * DIM + pb8];
      acc[0][f] = __builtin_amdgcn_mfma_f32_16x16x32_bf16(afr, b0, acc[0][f], 0, 0, 0);
      acc[1][f] = __builtin_amdgcn_mfma_f32_16x16x32_bf16(afr, b1, acc[1][f], 0, 0, 0);
    }
  }

  // epilogue: tile class decides format/offset
#pragma unroll
  for (int m = 0; m < 2; ++m){
    int node = m0 + wrow + m * 16 + l15;
    if (node >= N) continue;
    char* rb = Y + (size_t)node * ROWB;
#pragma unroll
    for (int f = 0; f < 8; ++f){
      int feat = f * 16 + quad * 4;
      f32x4 b4 = *(const f32x4*)&biascat[n0 + feat];
      f32x4 v  = acc[m][f];
      float a0 = v.x + b4.x, a1 = v.y + b4.y, a2 = v.z + b4.z, a3 = v.w + b4.w;
      if (nt < T){                       // q -> fp8
        u32 w = __builtin_amdgcn_cvt_pk_fp8_f32(a0, a1, 0, false);
        w = __builtin_amdgcn_cvt_pk_fp8_f32(a2, a3, w, true);
        *(u32*)(rb + nt * QV_SPAN + feat) = w;
      } else {
        u32 lo = f2bf(a0) | (f2bf(a1) << 16);
        u32 hi = f2bf(a2) | (f2bf(a3) << 16);
        u32x2 pk = {lo, hi};
        int boff;
        if (nt < 2*T)      boff = (nt - T) * QV_SPAN + 128;   // v
        else if (nt < 3*T) boff = K_OFF + (nt - 2*T) * 256;   // k
        else               boff = S_OFF;                      // s
        *(u32x2*)(rb + boff + feat * 2) = pk;
      }
    }
  }
}

// ---------------- aggregate + epilogue: 2 nodes per wave (32 lanes each) -----
__global__ __launch_bounds__(256) void agg_kernel(const char* __restrict__ Y,
                                                  const int* __restrict__ offs,
                                                  const int* __restrict__ boffs,
                                                  const int* __restrict__ packed,
                                                  float* __restrict__ out,
                                                  int N, int E, float invT){
  const int wave = threadIdx.x >> 6;
  const int lane = threadIdx.x & 63;
  const int half = lane >> 5;
  const int l32  = lane & 31;
  const int node = blockIdx.x * 8 + wave * 2 + half;
  const bool valid = node < N;
  const int nc = valid ? node : N - 1;

  const char* yr = Y + (size_t)nc * ROWB;

  // k (bf16) per type -> f32x4; s
  f32x4 kf[4];
#pragma unroll
  for (int t = 0; t < 4; ++t){
    u16x4 kw = *(const u16x4*)(yr + K_OFF + t * 256 + l32 * 8);
    kf[t] = (f32x4){ bf2f(kw.x), bf2f(kw.y), bf2f(kw.z), bf2f(kw.w) };
  }
  u16x4 sw = *(const u16x4*)(yr + S_OFF + l32 * 8);

  int e0 = 0, e1 = 0;
  if (valid){
    e0 = offs[nc] + boffs[nc >> 11];
    e1 = (nc == N - 1) ? E : (offs[nc + 1] + boffs[(nc + 1) >> 11]);
  }

  f32x4 acc = {0.f, 0.f, 0.f, 0.f};
  int e = e0;
  for (; e + 8 <= e1; e += 8){
    int p[8];
#pragma unroll
    for (int j = 0; j < 8; ++j) p[j] = packed[e + j];
    u32 qw[8]; u16x4 vw[8];
#pragma unroll
    for (int j = 0; j < 8; ++j){
      const char* sb = Y + (size_t)(p[j] >> 2) * ROWB + (p[j] & 3) * QV_SPAN;
      qw[j] = *(const u32*)(sb + l32 * 4);
      vw[j] = *(const u16x4*)(sb + 128 + l32 * 8);
    }
#pragma unroll
    for (int j = 0; j < 8; ++j){
      int t = p[j] & 3;
      f32x4 kt = (t == 0) ? kf[0] : (t == 1) ? kf[1] : (t == 2) ? kf[2] : kf[3];
      acc.x += bf2f(vw[j].x) * __builtin_amdgcn_rcpf(1.f + __expf(-(kt.x + __builtin_amdgcn_cvt_f32_fp8(qw[j], 0))));
      acc.y += bf2f(vw[j].y) * __builtin_amdgcn_rcpf(1.f + __expf(-(kt.y + __builtin_amdgcn_cvt_f32_fp8(qw[j], 1))));
      acc.z += bf2f(vw[j].z) * __builtin_amdgcn_rcpf(1.f + __expf(-(kt.z + __builtin_amdgcn_cvt_f32_fp8(qw[j], 2))));
      acc.w += bf2f(vw[j].w) * __builtin_amdgcn_rcpf(1.f + __expf(-(kt.w + __builtin_amdgcn_cvt_f32_fp8(qw[j], 3))));
    }
  }
  for (; e < e1; ++e){
    int p = packed[e];
    int t = p & 3;
    const char* sb = Y + (size_t)(p >> 2) * ROWB + t * QV_SPAN;
    u32 qw = *(const u32*)(sb + l32 * 4);
    u16x4 vw = *(const u16x4*)(sb + 128 + l32 * 8);
    f32x4 kt = (t == 0) ? kf[0] : (t == 1) ? kf[1] : (t == 2) ? kf[2] : kf[3];
    acc.x += bf2f(vw.x) * __builtin_amdgcn_rcpf(1.f + __expf(-(kt.x + __builtin_amdgcn_cvt_f32_fp8(qw, 0))));
    acc.y += bf2f(vw.y) * __builtin_amdgcn_rcpf(1.f + __expf(-(kt.y + __builtin_amdgcn_cvt_f32_fp8(qw, 1))));
    acc.z += bf2f(vw.z) * __builtin_amdgcn_rcpf(1.f + __expf(-(kt.z + __builtin_amdgcn_cvt_f32_fp8(qw, 2))));
    acc.w += bf2f(vw.w) * __builtin_amdgcn_rcpf(1.f + __expf(-(kt.w + __builtin_amdgcn_cvt_f32_fp8(qw, 3))));
  }
  if (valid){
    f32x4 o = { invT * acc.x + bf2f(sw.x), invT * acc.y + bf2f(sw.y),
                invT * acc.z + bf2f(sw.z), invT * acc.w + bf2f(sw.w) };
    *(f32x4*)&out[(size_t)node * DIM + l32 * 4] = o;
  }
}

// ---------------- launch -----------------------------------------------------
extern "C" void kernel_launch(void* const* d_in, const int* in_sizes, int n_in,
                              void* d_out, int out_size, void* d_ws, size_t ws_size,
                              hipStream_t stream){
  const float* x  = (const float*)d_in[0];
  const int*   ei = (const int*)d_in[1];
  const int*   et = (const int*)d_in[2];
  const float* Wk = (const float*)d_in[3];
  const float* bk = (const float*)d_in[4];
  const float* Wq = (const float*)d_in[5];
  const float* bq = (const float*)d_in[6];
  const float* Wv = (const float*)d_in[7];
  const float* bv = (const float*)d_in[8];
  const float* Ws = (const float*)d_in[9];
  const float* bb = (const float*)d_in[10];
  float* out = (float*)d_out;

  const int N = in_sizes[0] / DIM;
  const int E = in_sizes[2];
  const int T = in_sizes[3] / (DIM * DIM);
  const int NB = 3 * T + 1;
  const int ncol = NB * DIM;
  const int mtiles = (N + 127) / 128;
  const int rows = mtiles * 128;
  const int nscan = (N + 2047) / 2048;
  const int nsc = (E + 255) / 256;

  char* ws = (char*)d_ws;
  size_t off = 0;
  auto alloc = [&](size_t bytes) -> char* {
    char* p = ws + off;
    off = (off + bytes + 255) & ~(size_t)255;
    return p;
  };
  u16*   xb      = (u16*)alloc((size_t)rows * DIM * 2);
  u16*   WcatT   = (u16*)alloc((size_t)ncol * DIM * 2);
  float* biascat = (float*)alloc((size_t)ncol * 4);
  char*  Y       = (char*)alloc((size_t)rows * ROWB);
  int*   cnt     = (int*)alloc((size_t)N * 4);
  int*   offs    = (int*)alloc((size_t)N * 4);
  int*   rank    = (int*)alloc((size_t)E * 4);
  int*   packed  = (int*)alloc((size_t)E * 4);
  int*   bsum    = (int*)alloc((size_t)nscan * 4);
  int*   boffs   = (int*)alloc((size_t)nscan * 4);
  (void)ws_size; (void)n_in; (void)out_size;

  const int* srcp = ei;
  const int* dstp = ei + E;

  hipMemsetAsync(cnt, 0, (size_t)N * 4, stream);
  int prep_total = E + NB * DIM * DIM + rows * (DIM / 4);
  prep_kernel<<<(prep_total + 255) / 256, 256, 0, stream>>>(
      x, xb, dstp, cnt, rank, Wk, bk, Wq, bq, Wv, bv, Ws, bb,
      WcatT, biascat, T, N, E, rows);
  scan1_kernel<<<nscan, 256, 0, stream>>>(cnt, offs, bsum, N);
  scan2_kernel<<<1, 64, 0, stream>>>(bsum, boffs, nscan);
  gemm_scatter_kernel<<<nsc + NB * mtiles, 256, 0, stream>>>(
      xb, WcatT, biascat, Y, srcp, dstp, et, offs, boffs, rank, packed,
      N, E, T, NB, mtiles, nsc);
  agg_kernel<<<(N + 7) / 8, 256, 0, stream>>>(Y, offs, boffs, packed, out, N, E, 1.0f / (float)T);
}